// Round 7
// baseline (413.617 us; speedup 1.0000x reference)
//
#include <hip/hip_runtime.h>

#define BN 4096
#define BD 128
#define NB 4
#define TOPK 20
#define CAP 48                  // per-quarter candidate cap
#define SLOTS 192               // 4 * CAP
#define EPS 0.06f

typedef float f32x16 __attribute__((ext_vector_type(16)));
typedef short bf16x8 __attribute__((ext_vector_type(8)));

__device__ inline unsigned short f2bf(float f) {
  unsigned int u = __float_as_uint(f);
  unsigned int r = (u + 0x7FFFu + ((u >> 16) & 1u)) >> 16;
  return (unsigned short)r;
}

// ---------------- Projection (f64 accumulate) -> Qd, Kd (f64) + Khi (bf16) ----------------
__global__ __launch_bounds__(256) void proj_kernel(
    const float* __restrict__ x,
    const float* __restrict__ Wq, const float* __restrict__ bq,
    const float* __restrict__ Wk, const float* __restrict__ bk,
    double* __restrict__ Qd, double* __restrict__ Kd, unsigned short* __restrict__ Khi) {
  __shared__ double xs[32][129];
  const int tid = threadIdx.x;
  const long row0 = (long)blockIdx.x * 32;
  const float* xsrc = x + row0 * BD;
  for (int i = tid; i < 32 * BD; i += 256) xs[i >> 7][i & 127] = (double)xsrc[i];
  __syncthreads();

  const int e = tid & 127;
  const bool isK = tid >= 128;
  const float* W = isK ? Wk : Wq;
  const float* bias = isK ? bk : bq;
  double* Od = isK ? Kd : Qd;

  double acc[32];
  const double binit = (double)bias[e];
#pragma unroll
  for (int r = 0; r < 32; ++r) acc[r] = binit;

  for (int d = 0; d < BD; ++d) {
    const double wv = (double)W[d * BD + e];
#pragma unroll
    for (int r = 0; r < 32; ++r) acc[r] = fma(xs[r][d], wv, acc[r]);
  }

#pragma unroll
  for (int r = 0; r < 32; ++r) {
    const double a = acc[r];
    const long o = (row0 + r) * BD + e;
    Od[o] = a;
    if (isK) Khi[o] = f2bf((float)a);
  }
}

// ---------------- Screen (templated): MODE 0 = pool pass, MODE 1 = emit pass ----------------
// Grid 1024: block = (batch b, kv-quarter kq, rowgroup rg). 64 q-rows x 1024 kv.
// 8 waves = 4 kv-subtiles (kt) x 2 q-tiles (qt). kv chunk of 128 staged in double-buffered
// 32KB LDS halves, XOR-swizzled 16B slots (slot ^ (row&15)) -> 2-way conflicts only (free).
// MFMA D = K_tile(32x16) * Q_tile(16x32): C col(lane&31)=q, row((reg&3)+8*(reg>>2)+4*hi)=kv.
// MODE 0: per-lane top-2 -> poolG (bf16-trunc, subset of row scores -> valid tau bound).
// MODE 1: emit kv with screen-score >= tauG[row] into per-quarter segment (cap 48).
template <int MODE>
__global__ __launch_bounds__(512) void screen_kernel_t(
    const double* __restrict__ Qd, const unsigned short* __restrict__ Khi,
    unsigned int* __restrict__ poolG, const float* __restrict__ tauG,
    unsigned short* __restrict__ slistG, unsigned int* __restrict__ cnt4G) {
  __shared__ char kbuf[2][32768];
  __shared__ unsigned int scnt[MODE ? 64 : 1];
  __shared__ unsigned short slist[MODE ? 64 : 1][CAP];

  const int tid = threadIdx.x;
  const int lane = tid & 63;
  const int w = tid >> 6;
  const int kt = w & 3, qt = w >> 2;
  const int c31 = lane & 31, hi = lane >> 5;

  // XCD-affine block decode: all 64 blocks sharing (b,kq) land on one XCD (Khi slice L2-hot)
  const int blk = blockIdx.x;
  const int xcd = blk & 7;
  const int j = blk >> 3;                    // 0..127
  const int combo = xcd * 2 + (j & 1);       // 0..15
  const int b = combo >> 2;
  const int kq = combo & 3;
  const int rg = j >> 1;                     // 0..63
  const int rowbase = rg << 6;
  const int kvbase = kq << 10;

  const int qrow = qt * 32 + c31;
  const long grow = (long)b * BN + rowbase + qrow;
  const float RS = 0.088388347648318447f;

  // Q B-fragments: 8 k-steps of 16 (lane: col=c31, k = ks*16 + hi*8 + j)
  bf16x8 bqf[8];
  {
    const double* qp = Qd + grow * BD + hi * 8;
#pragma unroll
    for (int ks = 0; ks < 8; ++ks) {
      bf16x8 pk;
#pragma unroll
      for (int jj = 0; jj < 8; ++jj) pk[jj] = (short)f2bf((float)qp[ks * 16 + jj]);
      bqf[ks] = pk;
    }
  }

  float th = 0.0f;
  if constexpr (MODE == 1) {
    th = tauG[grow];
    if (tid < 64) scnt[tid] = 0;
  }

  const char* kb = (const char*)(Khi + ((long)b * BN + kvbase) * BD);
  const int ar = kt * 32 + c31;        // A-row within 128-kv chunk
  const int ar256 = ar * 256;
  const int arx = ar & 15;

  uint4 stg[4];
#define LOADSTG(s)                                                \
  {                                                               \
    const char* gsrc_ = kb + (long)(s)*32768 + tid * 16;          \
    stg[0] = *(const uint4*)(gsrc_);                              \
    stg[1] = *(const uint4*)(gsrc_ + 8192);                       \
    stg[2] = *(const uint4*)(gsrc_ + 16384);                      \
    stg[3] = *(const uint4*)(gsrc_ + 24576);                      \
  }
#define WRITESTG(pp)                                              \
  {                                                               \
    char* base_ = kbuf[pp];                                       \
    _Pragma("unroll") for (int j_ = 0; j_ < 4; ++j_) {            \
      const int L_ = j_ * 8192 + tid * 16;                        \
      const int r_ = L_ >> 8;                                     \
      const int c_ = (L_ >> 4) & 15;                              \
      *(uint4*)(base_ + r_ * 256 + ((c_ ^ (r_ & 15)) << 4)) = stg[j_]; \
    }                                                             \
  }

  float t1 = -3.4e38f, t2 = -3.4e38f;

  LOADSTG(0);
  WRITESTG(0);
  __syncthreads();

  for (int step = 0; step < 8; ++step) {
    const int p = step & 1;
    if (step < 7) LOADSTG(step + 1);

    f32x16 acc = {0.f, 0.f, 0.f, 0.f, 0.f, 0.f, 0.f, 0.f,
                  0.f, 0.f, 0.f, 0.f, 0.f, 0.f, 0.f, 0.f};
#pragma unroll
    for (int ks = 0; ks < 8; ++ks) {
      const bf16x8 a = *(const bf16x8*)(kbuf[p] + ar256 + (((ks * 2 + hi) ^ arx) << 4));
      acc = __builtin_amdgcn_mfma_f32_32x32x16_bf16(a, bqf[ks], acc, 0, 0, 0);
    }

#pragma unroll
    for (int reg = 0; reg < 16; ++reg) {
      const float s = acc[reg] * RS;
      if constexpr (MODE == 0) {
        const float w1 = fmaxf(t1, s);
        t2 = fmaxf(t2, fminf(t1, s));
        t1 = w1;
      } else {
        if (s >= th) {
          const int kv = kvbase + step * 128 + kt * 32 + ((reg & 3) + 8 * (reg >> 2) + 4 * hi);
          const unsigned int pidx = atomicAdd(&scnt[qrow], 1u);
          if (pidx < CAP) slist[qrow][pidx] = (unsigned short)kv;
        }
      }
    }

    if (step < 7) WRITESTG(p ^ 1);
    __syncthreads();
  }

  if constexpr (MODE == 0) {
    // pack top-2 as truncated bf16 (trunc of positive vals rounds down -> bound stays valid;
    // top-20 scores are always positive at these statistics)
    const unsigned int pk =
        ((__float_as_uint(t2) >> 16) << 16) | (__float_as_uint(t1) >> 16);
    poolG[grow * 32 + kq * 8 + kt * 2 + hi] = pk;
  } else {
    if (tid < 64) cnt4G[((long)b * BN + rowbase + tid) * 4 + kq] = min(scnt[tid], (unsigned int)CAP);
    for (int i = tid; i < 64 * CAP; i += 512) {
      const int r = i / CAP, c = i - (i / CAP) * CAP;
      slistG[((long)b * BN + rowbase + r) * SLOTS + kq * CAP + c] = slist[r][c];
    }
  }
#undef LOADSTG
#undef WRITESTG
}

// ---------------- Tau: 20th largest of the 64 pooled values per row, minus EPS ----------------
__global__ __launch_bounds__(512) void tau_kernel(
    const unsigned int* __restrict__ poolG, float* __restrict__ tauG) {
  const int tid = threadIdx.x;
  const int lane = tid & 63;
  const int w = tid >> 6;
  const long row = (long)blockIdx.x * 8 + w;

  const unsigned int pv = poolG[row * 32 + (lane >> 1)];
  float v = __uint_as_float((lane & 1) ? (pv & 0xFFFF0000u) : (pv << 16));

#pragma unroll
  for (int k = 2; k <= 64; k <<= 1) {
#pragma unroll
    for (int jj = k >> 1; jj > 0; jj >>= 1) {
      const float o = __shfl_xor(v, jj);
      const bool keepmin = (((lane & k) == 0) == ((lane & jj) == 0));
      v = keepmin ? fminf(v, o) : fmaxf(v, o);
    }
  }
  if (lane == 44) tauG[row] = v - EPS;   // idx 44 = 20th largest of 64 (ascending)
}

// ---------------- Finalize: wave-per-row, barrier-free, 3 keys/lane ----------------
__device__ inline float rescore_f64(const double2* __restrict__ kp2, const double2* __restrict__ q2) {
  double a0 = 0.0, a1 = 0.0, a2 = 0.0, a3 = 0.0;
#pragma unroll
  for (int i = 0; i < 64; i += 4) {
    a0 = fma(q2[i + 0].y, kp2[i + 0].y, fma(q2[i + 0].x, kp2[i + 0].x, a0));
    a1 = fma(q2[i + 1].y, kp2[i + 1].y, fma(q2[i + 1].x, kp2[i + 1].x, a1));
    a2 = fma(q2[i + 2].y, kp2[i + 2].y, fma(q2[i + 2].x, kp2[i + 2].x, a2));
    a3 = fma(q2[i + 3].y, kp2[i + 3].y, fma(q2[i + 3].x, kp2[i + 3].x, a3));
  }
  return (float)(((a0 + a1) + (a2 + a3)) * 8.8388347648318447e-02);
}

__device__ inline unsigned int fmono(float v) {
  const unsigned int u = __float_as_uint(v);
  return (u & 0x80000000u) ? ~u : (u | 0x80000000u);
}
__device__ inline float fdemono(unsigned int k) {
  const unsigned int u = (k & 0x80000000u) ? (k & 0x7fffffffu) : ~k;
  return __uint_as_float(u);
}

__global__ __launch_bounds__(256) void finalize_kernel(
    const double* __restrict__ Qd, const double* __restrict__ Kd,
    const unsigned short* __restrict__ slistG, const unsigned int* __restrict__ cnt4G,
    float* __restrict__ out) {
  const int tid = threadIdx.x;
  const int lane = tid & 63;
  const int w = tid >> 6;
  const int blk = blockIdx.x;
  const int b = (blk & 7) >> 1;                    // XCD-affinity: 2 XCDs per batch
  const int idx = ((blk >> 3) << 1) | (blk & 1);   // 0..1023
  const long row = (long)b * BN + idx * 4 + w;     // global q-row
  float* outrow = out + row * BN;
  const double* kb = Kd + (long)b * BN * BD;
  const double2* q2 = (const double2*)(Qd + row * BD);

  const uint4 c4 = *(const uint4*)(cnt4G + row * 4);

  // 3 candidate slots per lane, packed sortable key: (mono(val) << 12) | (4095 - col)
  unsigned long long key0 = 0ull, key1 = 0ull, key2 = 0ull;
#pragma unroll
  for (int t = 0; t < 3; ++t) {
    const int s = lane + t * 64;
    const int q = s / CAP;
    const int i = s - q * CAP;
    const unsigned int cq = (q & 1) ? ((q & 2) ? c4.w : c4.y) : ((q & 2) ? c4.z : c4.x);
    if ((unsigned int)i < cq) {
      const int kv = (int)slistG[row * SLOTS + s];
      const float v = rescore_f64((const double2*)(kb + (long)kv * BD), q2);
      const unsigned long long kk =
          ((unsigned long long)fmono(v) << 12) | (unsigned int)(4095 - kv);
      if (t == 0) key0 = kk;
      else if (t == 1) key1 = kk;
      else key2 = kk;
    }
  }
  // sort3 descending
  if (key1 > key0) { const unsigned long long t = key0; key0 = key1; key1 = t; }
  if (key2 > key1) { const unsigned long long t = key1; key1 = key2; key2 = t; }
  if (key1 > key0) { const unsigned long long t = key0; key0 = key1; key1 = t; }

  float m = 0.0f, se = 0.0f;
  float myval = 0.0f;
  int mycol = 0;
  for (int it = 0; it < TOPK; ++it) {
    unsigned long long rk = key0;
    for (int off = 32; off; off >>= 1) {
      const unsigned long long ok = __shfl_xor(rk, off);
      rk = (ok > rk) ? ok : rk;
    }
    const float rv = fdemono((unsigned int)(rk >> 12));
    if (it == 0) m = fmaxf(rv, 0.0f);
    se += expf(rv - m);
    if (lane == it) { myval = rv; mycol = 4095 - (int)(rk & 0xFFFull); }
    if (key0 == rk) { key0 = key1; key1 = key2; key2 = 0ull; }
  }

  const float Z = se + (float)(BN - TOPK) * expf(-m);
  const float c0 = expf(-m) / Z;

  // const fill of own row (coalesced float4), then fence, then scatter specials
  const float4 cv = make_float4(c0, c0, c0, c0);
  float4* op = (float4*)outrow;
#pragma unroll
  for (int i = 0; i < 16; ++i) op[i * 64 + lane] = cv;

  asm volatile("s_waitcnt vmcnt(0)" ::: "memory");
  if (lane < TOPK) outrow[mycol] = expf(myval - m) / Z;
}

extern "C" void kernel_launch(void* const* d_in, const int* in_sizes, int n_in,
                              void* d_out, int out_size, void* d_ws, size_t ws_size,
                              hipStream_t stream) {
  const float* x  = (const float*)d_in[0];
  const float* Wq = (const float*)d_in[1];
  const float* bq = (const float*)d_in[2];
  const float* Wk = (const float*)d_in[3];
  const float* bk = (const float*)d_in[4];
  float* out = (float*)d_out;

  const long NE = (long)NB * BN * BD;  // 2,097,152 elements
  double* Qd = (double*)d_ws;                              // 16 MB
  double* Kd = Qd + NE;                                    // 16 MB
  unsigned short* Khi = (unsigned short*)(Kd + NE);        // 4 MB
  unsigned short* slistG = Khi + NE;                       // 6 MB (16384 x 192 u16)
  unsigned int* poolG = (unsigned int*)slistG;             // 2 MB alias (dead before slistG written)
  unsigned int* cnt4G = (unsigned int*)(slistG + (long)NB * BN * SLOTS);  // 256 KB
  float* tauG = (float*)(cnt4G + (long)NB * BN * 4);       // 64 KB

  proj_kernel<<<NB * BN / 32, 256, 0, stream>>>(x, Wq, bq, Wk, bk, Qd, Kd, Khi);
  screen_kernel_t<0><<<1024, 512, 0, stream>>>(Qd, Khi, poolG, nullptr, nullptr, nullptr);
  tau_kernel<<<NB * BN / 8, 512, 0, stream>>>(poolG, tauG);
  screen_kernel_t<1><<<1024, 512, 0, stream>>>(Qd, Khi, nullptr, tauG, slistG, cnt4G);
  finalize_kernel<<<NB * BN / 4, 256, 0, stream>>>(Qd, Kd, slistG, cnt4G, out);
}

// Round 8
// 354.422 us; speedup vs baseline: 1.1670x; 1.1670x over previous
//
#include <hip/hip_runtime.h>

#define BN 4096
#define BD 128
#define NB 4
#define TOPK 20
#define CAP 48                  // per-quarter-block emission cap
#define SLOTS 192               // global per-row candidate cap (4 * CAP)
#define EPS_U 0.679f            // 0.06 / (1/sqrt(128)) -- unscaled score domain

typedef float f32x16 __attribute__((ext_vector_type(16)));
typedef short bf16x8 __attribute__((ext_vector_type(8)));

__device__ inline unsigned short f2bf(float f) {
  unsigned int u = __float_as_uint(f);
  unsigned int r = (u + 0x7FFFu + ((u >> 16) & 1u)) >> 16;
  return (unsigned short)r;
}

// ---------------- Projection (f64 accumulate) -> Qd, Kd (f64) + Khi (bf16) ----------------
__global__ __launch_bounds__(256) void proj_kernel(
    const float* __restrict__ x,
    const float* __restrict__ Wq, const float* __restrict__ bq,
    const float* __restrict__ Wk, const float* __restrict__ bk,
    double* __restrict__ Qd, double* __restrict__ Kd, unsigned short* __restrict__ Khi) {
  __shared__ double xs[32][129];
  const int tid = threadIdx.x;
  const long row0 = (long)blockIdx.x * 32;
  const float* xsrc = x + row0 * BD;
  for (int i = tid; i < 32 * BD; i += 256) xs[i >> 7][i & 127] = (double)xsrc[i];
  __syncthreads();

  const int e = tid & 127;
  const bool isK = tid >= 128;
  const float* W = isK ? Wk : Wq;
  const float* bias = isK ? bk : bq;
  double* Od = isK ? Kd : Qd;

  double acc[32];
  const double binit = (double)bias[e];
#pragma unroll
  for (int r = 0; r < 32; ++r) acc[r] = binit;

  for (int d = 0; d < BD; ++d) {
    const double wv = (double)W[d * BD + e];
#pragma unroll
    for (int r = 0; r < 32; ++r) acc[r] = fma(xs[r][d], wv, acc[r]);
  }

#pragma unroll
  for (int r = 0; r < 32; ++r) {
    const double a = acc[r];
    const long o = (row0 + r) * BD + e;
    Od[o] = a;
    if (isK) Khi[o] = f2bf((float)a);
  }
}

// ---------------- Screen (templated): MODE 0 = pool pass, MODE 1 = emit pass ----------------
// Scores kept UNSCALED (no 1/sqrt(D)) in both passes; tau/EPS in the same domain.
template <int MODE>
__global__ __launch_bounds__(512) void screen_kernel_t(
    const double* __restrict__ Qd, const unsigned short* __restrict__ Khi,
    unsigned int* __restrict__ poolG, const float* __restrict__ tauG,
    unsigned short* __restrict__ listG, unsigned int* __restrict__ cntG) {
  __shared__ char kbuf[2][32768];
  __shared__ unsigned int scnt[MODE ? 64 : 1];
  __shared__ unsigned int sbase[MODE ? 64 : 1];
  __shared__ unsigned short slist[MODE ? 64 : 1][CAP];

  const int tid = threadIdx.x;
  const int lane = tid & 63;
  const int w = tid >> 6;
  const int kt = w & 3, qt = w >> 2;
  const int c31 = lane & 31, hi = lane >> 5;

  // XCD-affine decode: all 64 blocks sharing (b,kq) on one XCD
  const int blk = blockIdx.x;
  const int xcd = blk & 7;
  const int j = blk >> 3;
  const int combo = xcd * 2 + (j & 1);
  const int b = combo >> 2;
  const int kq = combo & 3;
  const int rg = j >> 1;
  const int rowbase = rg << 6;
  const int kvbase = kq << 10;

  const int qrow = qt * 32 + c31;
  const long grow = (long)b * BN + rowbase + qrow;

  bf16x8 bqf[8];
  {
    const double* qp = Qd + grow * BD + hi * 8;
#pragma unroll
    for (int ks = 0; ks < 8; ++ks) {
      bf16x8 pk;
#pragma unroll
      for (int jj = 0; jj < 8; ++jj) pk[jj] = (short)f2bf((float)qp[ks * 16 + jj]);
      bqf[ks] = pk;
    }
  }

  float th = 0.0f;
  if constexpr (MODE == 1) {
    th = tauG[grow];
    if (tid < 64) scnt[tid] = 0;
  }

  const char* kb = (const char*)(Khi + ((long)b * BN + kvbase) * BD);
  const int ar = kt * 32 + c31;
  const int ar256 = ar * 256;
  const int arx = ar & 15;

  uint4 stg[4];
#define LOADSTG(s)                                                \
  {                                                               \
    const char* gsrc_ = kb + (long)(s)*32768 + tid * 16;          \
    stg[0] = *(const uint4*)(gsrc_);                              \
    stg[1] = *(const uint4*)(gsrc_ + 8192);                       \
    stg[2] = *(const uint4*)(gsrc_ + 16384);                      \
    stg[3] = *(const uint4*)(gsrc_ + 24576);                      \
  }
#define WRITESTG(pp)                                              \
  {                                                               \
    char* base_ = kbuf[pp];                                       \
    _Pragma("unroll") for (int j_ = 0; j_ < 4; ++j_) {            \
      const int L_ = j_ * 8192 + tid * 16;                        \
      const int r_ = L_ >> 8;                                     \
      const int c_ = (L_ >> 4) & 15;                              \
      *(uint4*)(base_ + r_ * 256 + ((c_ ^ (r_ & 15)) << 4)) = stg[j_]; \
    }                                                             \
  }

  float t1 = -3.4e38f, t2 = -3.4e38f;

  LOADSTG(0);
  WRITESTG(0);
  __syncthreads();

  for (int step = 0; step < 8; ++step) {
    const int p = step & 1;
    if (step < 7) LOADSTG(step + 1);

    f32x16 acc = {0.f, 0.f, 0.f, 0.f, 0.f, 0.f, 0.f, 0.f,
                  0.f, 0.f, 0.f, 0.f, 0.f, 0.f, 0.f, 0.f};
#pragma unroll
    for (int ks = 0; ks < 8; ++ks) {
      const bf16x8 a = *(const bf16x8*)(kbuf[p] + ar256 + (((ks * 2 + hi) ^ arx) << 4));
      acc = __builtin_amdgcn_mfma_f32_32x32x16_bf16(a, bqf[ks], acc, 0, 0, 0);
    }

#pragma unroll
    for (int reg = 0; reg < 16; ++reg) {
      const float s = acc[reg];
      if constexpr (MODE == 0) {
        const float w1 = fmaxf(t1, s);
        t2 = fmaxf(t2, fminf(t1, s));
        t1 = w1;
      } else {
        if (s >= th) {
          const int kv = kvbase + step * 128 + kt * 32 + ((reg & 3) + 8 * (reg >> 2) + 4 * hi);
          const unsigned int pidx = atomicAdd(&scnt[qrow], 1u);
          if (pidx < CAP) slist[qrow][pidx] = (unsigned short)kv;
        }
      }
    }

    if (step < 7) WRITESTG(p ^ 1);
    __syncthreads();
  }

  if constexpr (MODE == 0) {
    const unsigned int pk =
        ((__float_as_uint(t2) >> 16) << 16) | (__float_as_uint(t1) >> 16);
    poolG[grow * 32 + kq * 8 + kt * 2 + hi] = pk;
  } else {
    // compact into one global per-row list (order-nondeterministic across quarters;
    // final selection is order-invariant max-key extraction -> deterministic output)
    if (tid < 64) {
      const unsigned int n = min(scnt[tid], (unsigned int)CAP);
      scnt[tid] = n;
      sbase[tid] = atomicAdd(&cntG[(long)b * BN + rowbase + tid], n);
    }
    __syncthreads();
    for (int i = tid; i < 64 * CAP; i += 512) {
      const int r = i / CAP, c = i - (i / CAP) * CAP;
      if ((unsigned int)c < scnt[r])
        listG[((long)b * BN + rowbase + r) * SLOTS + sbase[r] + c] = slist[r][c];
    }
  }
#undef LOADSTG
#undef WRITESTG
}

// ---------------- Tau: 20th largest of 64 pooled values (unscaled) - EPS; also zero cntG ----------------
__global__ __launch_bounds__(512) void tau_kernel(
    const unsigned int* __restrict__ poolG, float* __restrict__ tauG,
    unsigned int* __restrict__ cntG) {
  const int tid = threadIdx.x;
  const int lane = tid & 63;
  const int w = tid >> 6;
  const long row = (long)blockIdx.x * 8 + w;

  const unsigned int pv = poolG[row * 32 + (lane >> 1)];
  float v = __uint_as_float((lane & 1) ? (pv & 0xFFFF0000u) : (pv << 16));

#pragma unroll
  for (int k = 2; k <= 64; k <<= 1) {
#pragma unroll
    for (int jj = k >> 1; jj > 0; jj >>= 1) {
      const float o = __shfl_xor(v, jj);
      const bool keepmin = (((lane & k) == 0) == ((lane & jj) == 0));
      v = keepmin ? fminf(v, o) : fmaxf(v, o);
    }
  }
  if (lane == 44) tauG[row] = v - EPS_U;
  if (lane == 0) cntG[row] = 0;
}

// ---------------- TopK: rescore compacted candidates, write per-row record ----------------
__device__ inline float rescore_f64(const double2* __restrict__ kp2, const double2* __restrict__ q2) {
  double a0 = 0.0, a1 = 0.0, a2 = 0.0, a3 = 0.0;
#pragma unroll
  for (int i = 0; i < 64; i += 4) {
    a0 = fma(q2[i + 0].y, kp2[i + 0].y, fma(q2[i + 0].x, kp2[i + 0].x, a0));
    a1 = fma(q2[i + 1].y, kp2[i + 1].y, fma(q2[i + 1].x, kp2[i + 1].x, a1));
    a2 = fma(q2[i + 2].y, kp2[i + 2].y, fma(q2[i + 2].x, kp2[i + 2].x, a2));
    a3 = fma(q2[i + 3].y, kp2[i + 3].y, fma(q2[i + 3].x, kp2[i + 3].x, a3));
  }
  return (float)(((a0 + a1) + (a2 + a3)) * 8.8388347648318447e-02);
}

__device__ inline unsigned int fmono(float v) {
  const unsigned int u = __float_as_uint(v);
  return (u & 0x80000000u) ? ~u : (u | 0x80000000u);
}
__device__ inline float fdemono(unsigned int k) {
  const unsigned int u = (k & 0x80000000u) ? (k & 0x7fffffffu) : ~k;
  return __uint_as_float(u);
}

// rec layout per row (48 u32): [0..19] prob(f32), [20..39] col(u32), [40] c0(f32)
__global__ __launch_bounds__(256) void topk_kernel(
    const double* __restrict__ Qd, const double* __restrict__ Kd,
    const unsigned short* __restrict__ listG, const unsigned int* __restrict__ cntG,
    unsigned int* __restrict__ rec) {
  const int tid = threadIdx.x;
  const int lane = tid & 63;
  const int w = tid >> 6;
  const int blk = blockIdx.x;
  const int b = (blk & 7) >> 1;                    // XCD-affinity: 2 XCDs per batch
  const int idx = ((blk >> 3) << 1) | (blk & 1);   // 0..1023
  const long row = (long)b * BN + idx * 4 + w;
  const double* kb = Kd + (long)b * BN * BD;
  const double2* q2 = (const double2*)(Qd + row * BD);

  const int c = (int)min(cntG[row], (unsigned int)SLOTS);

  unsigned long long key0 = 0ull, key1 = 0ull, key2 = 0ull;
  if (lane < c) {
    const int kv = (int)listG[row * SLOTS + lane];
    const float v = rescore_f64((const double2*)(kb + (long)kv * BD), q2);
    key0 = ((unsigned long long)fmono(v) << 12) | (unsigned int)(4095 - kv);
  }
  if (c > 64) {
    if (lane + 64 < c) {
      const int kv = (int)listG[row * SLOTS + lane + 64];
      const float v = rescore_f64((const double2*)(kb + (long)kv * BD), q2);
      key1 = ((unsigned long long)fmono(v) << 12) | (unsigned int)(4095 - kv);
    }
    if (c > 128 && lane + 128 < c) {
      const int kv = (int)listG[row * SLOTS + lane + 128];
      const float v = rescore_f64((const double2*)(kb + (long)kv * BD), q2);
      key2 = ((unsigned long long)fmono(v) << 12) | (unsigned int)(4095 - kv);
    }
    if (key1 > key0) { const unsigned long long t = key0; key0 = key1; key1 = t; }
    if (key2 > key1) { const unsigned long long t = key1; key1 = key2; key2 = t; }
    if (key1 > key0) { const unsigned long long t = key0; key0 = key1; key1 = t; }
  }

  float m = 0.0f, se = 0.0f;
  float myval = 0.0f;
  int mycol = 0;
  for (int it = 0; it < TOPK; ++it) {
    unsigned long long rk = key0;
    for (int off = 32; off; off >>= 1) {
      const unsigned long long ok = __shfl_xor(rk, off);
      rk = (ok > rk) ? ok : rk;
    }
    const float rv = fdemono((unsigned int)(rk >> 12));
    if (it == 0) m = fmaxf(rv, 0.0f);
    se += expf(rv - m);
    if (lane == it) { myval = rv; mycol = 4095 - (int)(rk & 0xFFFull); }
    if (key0 == rk) { key0 = key1; key1 = key2; key2 = 0ull; }
  }

  const float Z = se + (float)(BN - TOPK) * expf(-m);
  unsigned int* rr = rec + row * 48;
  if (lane < TOPK) {
    rr[lane] = __float_as_uint(expf(myval - m) / Z);
    rr[20 + lane] = (unsigned int)mycol;
  }
  if (lane == 0) rr[40] = __float_as_uint(expf(-m) / Z);
}

// ---------------- Fill: stream one row per block, patch specials via LDS bitmap ----------------
__global__ __launch_bounds__(256) void fill_kernel(
    const unsigned int* __restrict__ rec, float* __restrict__ out) {
  __shared__ unsigned int bm[128];
  __shared__ float pv[TOPK];
  __shared__ int pc[TOPK];
  __shared__ float sc0;

  const int tid = threadIdx.x;
  const long row = blockIdx.x;
  const unsigned int* rr = rec + row * 48;

  if (tid < 128) bm[tid] = 0;
  __syncthreads();
  if (tid < TOPK) {
    pv[tid] = __uint_as_float(rr[tid]);
    const int col = (int)rr[20 + tid];
    pc[tid] = col;
    atomicOr(&bm[col >> 5], 1u << (col & 31));
  }
  if (tid == TOPK) sc0 = __uint_as_float(rr[40]);
  __syncthreads();

  const float c0 = sc0;
  const float4 cv = make_float4(c0, c0, c0, c0);
  float4* op = (float4*)(out + row * BN);

#pragma unroll
  for (int k = 0; k < 4; ++k) {
    const int j = tid + k * 256;                   // float4 index 0..1023
    const unsigned int bits = (bm[j >> 3] >> ((j & 7) * 4)) & 0xFu;
    if (bits == 0u) {
      op[j] = cv;
    } else {
      float4 v = cv;
      const int col0 = j * 4;
#pragma unroll
      for (int cmp = 0; cmp < 4; ++cmp) {
        if ((bits >> cmp) & 1u) {
          const int col = col0 + cmp;
          float pvv = c0;
          for (int i = 0; i < TOPK; ++i)
            if (pc[i] == col) pvv = pv[i];
          (&v.x)[cmp] = pvv;
        }
      }
      op[j] = v;
    }
  }
}

extern "C" void kernel_launch(void* const* d_in, const int* in_sizes, int n_in,
                              void* d_out, int out_size, void* d_ws, size_t ws_size,
                              hipStream_t stream) {
  const float* x  = (const float*)d_in[0];
  const float* Wq = (const float*)d_in[1];
  const float* bq = (const float*)d_in[2];
  const float* Wk = (const float*)d_in[3];
  const float* bk = (const float*)d_in[4];
  float* out = (float*)d_out;

  const long NE = (long)NB * BN * BD;  // 2,097,152 elements
  const long NR = (long)NB * BN;       // 16384 rows
  double* Qd = (double*)d_ws;                              // 16 MB
  double* Kd = Qd + NE;                                    // 16 MB
  unsigned short* Khi = (unsigned short*)(Kd + NE);        // 4 MB
  unsigned short* listG = Khi + NE;                        // 6 MB (NR x SLOTS u16)
  unsigned int* poolG = (unsigned int*)listG;              // 2 MB alias (dead before listG)
  unsigned int* cntG = (unsigned int*)(listG + NR * SLOTS);// 64 KB
  float* tauG = (float*)(cntG + NR);                       // 64 KB
  unsigned int* rec = (unsigned int*)(tauG + NR);          // 3 MB (NR x 48 u32)

  proj_kernel<<<NB * BN / 32, 256, 0, stream>>>(x, Wq, bq, Wk, bk, Qd, Kd, Khi);
  screen_kernel_t<0><<<1024, 512, 0, stream>>>(Qd, Khi, poolG, nullptr, nullptr, nullptr);
  tau_kernel<<<NR / 8, 512, 0, stream>>>(poolG, tauG, cntG);
  screen_kernel_t<1><<<1024, 512, 0, stream>>>(Qd, Khi, nullptr, tauG, listG, cntG);
  topk_kernel<<<NR / 4, 256, 0, stream>>>(Qd, Kd, listG, cntG, rec);
  fill_kernel<<<NR, 256, 0, stream>>>(rec, out);
}